// Round 11
// baseline (225.101 us; speedup 1.0000x reference)
//
#include <hip/hip_runtime.h>
#include <hip/hip_bf16.h>
#include <math.h>

#define BB 16384
#define DD 768
#define MPAD 16640             // 16384 + 84 table rows + zero pad (multiple of 128)

typedef __attribute__((ext_vector_type(8))) short bf16x8;
typedef __attribute__((ext_vector_type(4))) float f32x4;

// Static device scratch — referenced ONLY from device code.
__device__ short g_Abf[(size_t)MPAD * DD];          // bf16 feats
__device__ short g_W[(size_t)2304 * DD];            // bf16 in_proj_w (Wq|Wk|Wv rows)
__device__ short g_WoutBf[(size_t)DD * DD];         // bf16 out_proj_w
__device__ short g_qkv[(size_t)MPAD * 2304];        // bf16 GEMM1 out: q|k|v per row (no bias)
__device__ short g_mixed[(size_t)BB * DD];          // bf16 attention-mixed v (+bias)
__device__ short g_pre[(size_t)BB * DD];            // bf16 GEMM2 out (no bias)
__device__ float g_maxabs;

__device__ inline unsigned short f2bf(float x) {
    union { float f; unsigned u; } v; v.f = x;
    unsigned r = v.u + 0x7fffu + ((v.u >> 16) & 1u);
    return (unsigned short)(r >> 16);
}
__device__ inline float bf2f(unsigned short h) {
    union { unsigned u; float f; } v; v.u = ((unsigned)h) << 16;
    return v.f;
}

__device__ inline float gelu_exact(float x) {
    return 0.5f * x * (1.0f + erff(x * 0.70710678118654752440f));
}

__device__ inline float block_sum256(float v, float* sbuf) {
    #pragma unroll
    for (int o = 32; o; o >>= 1) v += __shfl_xor(v, o);
    __syncthreads();
    if ((threadIdx.x & 63) == 0) sbuf[threadIdx.x >> 6] = v;
    __syncthreads();
    return sbuf[0] + sbuf[1] + sbuf[2] + sbuf[3];
}

// single block, 1024 threads: max|x| -> g_maxabs
__global__ __launch_bounds__(1024) void k_absmax(const float* __restrict__ number) {
    const float4* n4 = reinterpret_cast<const float4*>(number);
    float v = 0.f;
    #pragma unroll
    for (int i = 0; i < 4; ++i) {
        float4 x = n4[threadIdx.x + 1024 * i];
        v = fmaxf(fmaxf(fabsf(x.x), fabsf(x.y)), fmaxf(fmaxf(fabsf(x.z), fabsf(x.w)), v));
    }
    #pragma unroll
    for (int o = 32; o; o >>= 1) v = fmaxf(v, __shfl_xor(v, o));
    __shared__ float sb[16];
    if ((threadIdx.x & 63) == 0) sb[threadIdx.x >> 6] = v;
    __syncthreads();
    if (threadIdx.x == 0) {
        float m = sb[0];
        #pragma unroll
        for (int i = 1; i < 16; ++i) m = fmaxf(m, sb[i]);
        g_maxabs = m;
    }
}

// blocks: 0-19 mag rows, 20-35 scale rows, 36-83 ctx rows, 84-255 zero pad rows,
// 256-2559 weight cast (in_proj_w + out_proj_w -> bf16).
__global__ void k_tables(const float* __restrict__ mag_emb,
                         const float* __restrict__ se_w1, const float* __restrict__ se_b1,
                         const float* __restrict__ se_g1, const float* __restrict__ se_bt1,
                         const float* __restrict__ se_w2, const float* __restrict__ se_b2,
                         const float* __restrict__ ce_w, const float* __restrict__ ce_b,
                         const float* __restrict__ ce_g, const float* __restrict__ ce_bt,
                         const float* __restrict__ in_proj_w, const float* __restrict__ out_proj_w) {
    __shared__ float sbuf[4];
    __shared__ float sh[192];
    const int t = threadIdx.x;
    const int blk = blockIdx.x;
    if (blk < 20) {
        #pragma unroll
        for (int i = 0; i < 3; ++i) {
            int d = t + 256 * i;
            g_Abf[(size_t)(BB + blk) * DD + d] = (short)f2bf(mag_emb[blk * DD + d]);
        }
    } else if (blk < 36) {
        int sfi = blk - 20;
        float sf = (float)(sfi - 10);
        float pre = 0.f;
        if (t < 192) pre = sf * se_w1[t] + se_b1[t];
        float s = block_sum256(t < 192 ? pre : 0.f, sbuf);
        float m = s / 192.f;
        float dd = (t < 192) ? (pre - m) : 0.f;
        float vv = block_sum256(dd * dd, sbuf);
        float inv = 1.f / sqrtf(vv / 192.f + 1e-5f);
        if (t < 192) sh[t] = gelu_exact((pre - m) * inv * se_g1[t] + se_bt1[t]);
        __syncthreads();
        #pragma unroll
        for (int i = 0; i < 3; ++i) {
            int d = t + 256 * i;
            float acc = se_b2[d];
            for (int j = 0; j < 192; ++j) acc += se_w2[d * 192 + j] * sh[j];
            g_Abf[(size_t)(BB + 20 + sfi) * DD + d] = (short)f2bf(acc);
        }
    } else if (blk < 84) {
        int c = blk - 36;
        int si = c >> 4, sfi = c & 15;
        float f0 = (float)(si - 1);
        float f1 = (float)(sfi - 10) / 16.f;
        float pre[3];
        float ps = 0.f;
        #pragma unroll
        for (int i = 0; i < 3; ++i) {
            int d = t + 256 * i;
            pre[i] = f0 * ce_w[2 * d] + f1 * ce_w[2 * d + 1] + ce_b[d];
            ps += pre[i];
        }
        float s = block_sum256(ps, sbuf);
        float m = s / 768.f;
        float qs = 0.f;
        #pragma unroll
        for (int i = 0; i < 3; ++i) { float dd = pre[i] - m; qs += dd * dd; }
        float vv = block_sum256(qs, sbuf);
        float inv = 1.f / sqrtf(vv / 768.f + 1e-5f);
        #pragma unroll
        for (int i = 0; i < 3; ++i) {
            int d = t + 256 * i;
            g_Abf[(size_t)(BB + 36 + c) * DD + d] =
                (short)f2bf(gelu_exact((pre[i] - m) * inv * ce_g[d] + ce_bt[d]));
        }
    } else if (blk < 256) {
        int row = BB + 84 + (blk - 84);    // 16468 .. 16639
        #pragma unroll
        for (int i = 0; i < 3; ++i) g_Abf[(size_t)row * DD + t + 256 * i] = 0;
    } else {
        int i = (blk - 256) * 256 + t;
        const bool second = (i >= 442368);
        const float* src = second ? out_proj_w : in_proj_w;
        short* dst = second ? g_WoutBf : g_W;
        int j = second ? (i - 442368) : i;
        const float4 v = *reinterpret_cast<const float4*>(&src[(size_t)j * 4]);
        ushort4 o;
        o.x = f2bf(v.x); o.y = f2bf(v.y); o.z = f2bf(v.z); o.w = f2bf(v.w);
        *reinterpret_cast<ushort4*>(&dst[(size_t)j * 4]) = o;
    }
}

// one wave per element: num_enc row (fp32 math, bf16 store)
__global__ void k_numenc(const float* __restrict__ number,
                         const float* __restrict__ ne_w, const float* __restrict__ ne_b,
                         const float* __restrict__ ne_g, const float* __restrict__ ne_bt) {
    const int wid = threadIdx.x >> 6, lane = threadIdx.x & 63;
    const int e = blockIdx.x * 4 + wid;
    const float ma = g_maxabs;
    const float x = number[e];
    const float a = x / (ma + 1e-10f);
    const float b = log1pf(fabsf(x)) / (log1pf(ma) + 1e-10f);
    float pre[12];
    float s = 0.f;
    #pragma unroll
    for (int j = 0; j < 12; ++j) {
        int d = lane + 64 * j;
        float2 w = *reinterpret_cast<const float2*>(&ne_w[2 * d]);
        pre[j] = a * w.x + b * w.y + ne_b[d];
        s += pre[j];
    }
    #pragma unroll
    for (int o = 32; o; o >>= 1) s += __shfl_xor(s, o);
    float m = s / 768.f;
    float q = 0.f;
    #pragma unroll
    for (int j = 0; j < 12; ++j) { float dd = pre[j] - m; q += dd * dd; }
    #pragma unroll
    for (int o = 32; o; o >>= 1) q += __shfl_xor(q, o);
    float inv = 1.f / sqrtf(q / 768.f + 1e-5f);
    #pragma unroll
    for (int j = 0; j < 12; ++j) {
        int d = lane + 64 * j;
        g_Abf[(size_t)e * DD + d] = (short)f2bf(gelu_exact((pre[j] - m) * inv * ne_g[d] + ne_bt[d]));
    }
}

// C[m][n] = sum_k A[m][k] * B[n][k]  (bf16 in/out, fp32 MFMA accum)
// which==0: A=g_Abf (M=16640), B=g_W,       C=g_qkv (N=2304)
// which==1: A=g_mixed (M=16384), B=g_WoutBf, C=g_pre (N=768)
// R11 SHAPE: 128x128 tile, BK=64, 256 threads / 4 waves arranged 2Mx2N,
// wave-tile 64x64 (acc 64 VGPR). __launch_bounds__(256,4): ~110 total VGPR ->
// 4 waves/SIMD; LDS 32KB -> 4 BLOCKS/CU co-resident. Keeps R10's 32 MFMA per
// wave per K-step AND doubles independent barrier streams per CU (R10 had 2
// lockstep 8-wave blocks; now 4 x 4-wave blocks stagger so one block's stage
// latency hides under another's MFMA — the m114 implicit-overlap regime).
// 1-phase, gload_lds w16 linear-dest + inverse-swizzled source, 8-slot XOR
// swizzle on read. Bijective XCD swizzle.
__global__ __launch_bounds__(256, 4) void gemm_bt(int which, int N, int K) {
    const short* A = (which == 0) ? g_Abf : g_mixed;
    const short* B = (which == 0) ? g_W : g_WoutBf;
    short* C = (which == 0) ? g_qkv : g_pre;

    __shared__ short As[128 * 64];             // 16 KB
    __shared__ short Bs[128 * 64];             // 16 KB
    const int t = threadIdx.x;

    const int GX = gridDim.x;
    const int nwg = GX * gridDim.y;
    const int lin = blockIdx.y * GX + blockIdx.x;
    const int qq = nwg >> 3, rr = nwg & 7;
    const int xcd = lin & 7, idx = lin >> 3;
    const int nl = (xcd < rr ? xcd * (qq + 1) : rr * (qq + 1) + (xcd - rr) * qq) + idx;
    const int m0 = (nl / GX) * 128, n0 = (nl % GX) * 128;

    const int wid = t >> 6, lane = t & 63;
    const int wm = wid >> 1, wn = wid & 1;      // 2 x 2 waves, wave tile 64x64
    const int fr = lane & 15, ks = lane >> 4;

    f32x4 acc[4][4];
    #pragma unroll
    for (int m = 0; m < 4; ++m)
        #pragma unroll
        for (int n = 0; n < 4; ++n) acc[m][n] = (f32x4){0.f, 0.f, 0.f, 0.f};

    for (int k0 = 0; k0 < K; k0 += 64) {
        // stage A and B: 128x64 each = 1024 16B-slots, 4 issues/thread/tile
        #pragma unroll
        for (int i = 0; i < 4; ++i) {
            int L = t + 256 * i;
            int row = L >> 3, sp = L & 7;
            int s = sp ^ (row & 7);
            const short* srcA = A + (size_t)(m0 + row) * K + k0 + s * 8;
            const short* srcB = B + (size_t)(n0 + row) * K + k0 + s * 8;
            __builtin_amdgcn_global_load_lds(
                (const __attribute__((address_space(1))) unsigned int*)srcA,
                (__attribute__((address_space(3))) unsigned int*)((char*)As + L * 16), 16, 0, 0);
            __builtin_amdgcn_global_load_lds(
                (const __attribute__((address_space(1))) unsigned int*)srcB,
                (__attribute__((address_space(3))) unsigned int*)((char*)Bs + L * 16), 16, 0, 0);
        }
        __syncthreads();
        #pragma unroll
        for (int kk = 0; kk < 2; ++kk) {
            bf16x8 af[4], bfr[4];
            #pragma unroll
            for (int m = 0; m < 4; ++m) {
                int row = wm * 64 + m * 16 + fr;
                int off = row * 128 + ((((kk << 2) | ks) ^ (row & 7)) * 16);
                af[m] = *(const bf16x8*)((const char*)As + off);
            }
            #pragma unroll
            for (int n = 0; n < 4; ++n) {
                int row = wn * 64 + n * 16 + fr;
                int off = row * 128 + ((((kk << 2) | ks) ^ (row & 7)) * 16);
                bfr[n] = *(const bf16x8*)((const char*)Bs + off);
            }
            #pragma unroll
            for (int m = 0; m < 4; ++m)
                #pragma unroll
                for (int n = 0; n < 4; ++n)
                    acc[m][n] = __builtin_amdgcn_mfma_f32_16x16x32_bf16(af[m], bfr[n], acc[m][n], 0, 0, 0);
        }
        __syncthreads();
    }

    #pragma unroll
    for (int m = 0; m < 4; ++m)
        #pragma unroll
        for (int n = 0; n < 4; ++n)
            #pragma unroll
            for (int j = 0; j < 4; ++j) {
                int row = m0 + wm * 64 + m * 16 + ks * 4 + j;
                int col = n0 + wn * 64 + n * 16 + fr;
                C[(size_t)row * N + col] = (short)f2bf(acc[m][n][j]);
            }
}

// fused attention + per-head mix IN V-SPACE. One wave per element; 12 dims/lane;
// head h = lane/8. Vectorized ushort4/float4 loads (G13).
__global__ void k_attn_mix(const float* __restrict__ number, const float* __restrict__ boundaries,
                           const float* __restrict__ in_proj_b) {
    const int wid = threadIdx.x >> 6, lane = threadIdx.x & 63;
    const int e = blockIdx.x * 4 + wid;
    const float x = number[e];
    int bin = 0;
    #pragma unroll
    for (int j = 0; j < 20; ++j) bin += (boundaries[j] < x) ? 1 : 0;
    bin = min(bin, 19);
    float sf = floorf(log10f(fabsf(x) + 1e-10f));
    int sfi = min(max((int)sf + 10, 0), 15);
    int si = (x > 0.f) ? 2 : ((x < 0.f) ? 0 : 1);
    int rows[4] = {e, BB + bin, BB + 20 + sfi, BB + 36 + si * 16 + sfi};

    const int d0 = lane * 12;
    float bq[12], bk[12], bv[12];
    #pragma unroll
    for (int c4 = 0; c4 < 3; ++c4) {
        float4 a = *reinterpret_cast<const float4*>(&in_proj_b[d0 + c4 * 4]);
        float4 b = *reinterpret_cast<const float4*>(&in_proj_b[768 + d0 + c4 * 4]);
        float4 c = *reinterpret_cast<const float4*>(&in_proj_b[1536 + d0 + c4 * 4]);
        bq[c4 * 4 + 0] = a.x; bq[c4 * 4 + 1] = a.y; bq[c4 * 4 + 2] = a.z; bq[c4 * 4 + 3] = a.w;
        bk[c4 * 4 + 0] = b.x; bk[c4 * 4 + 1] = b.y; bk[c4 * 4 + 2] = b.z; bk[c4 * 4 + 3] = b.w;
        bv[c4 * 4 + 0] = c.x; bv[c4 * 4 + 1] = c.y; bv[c4 * 4 + 2] = c.z; bv[c4 * 4 + 3] = c.w;
    }
    float q[4][12], k[4][12], v[4][12];
    #pragma unroll
    for (int i = 0; i < 4; ++i) {
        const unsigned short* base = (const unsigned short*)&g_qkv[(size_t)rows[i] * 2304 + d0];
        #pragma unroll
        for (int c4 = 0; c4 < 3; ++c4) {
            ushort4 uq = *reinterpret_cast<const ushort4*>(base + c4 * 4);
            ushort4 uk = *reinterpret_cast<const ushort4*>(base + 768 + c4 * 4);
            ushort4 uv = *reinterpret_cast<const ushort4*>(base + 1536 + c4 * 4);
            q[i][c4 * 4 + 0] = bf2f(uq.x) + bq[c4 * 4 + 0];
            q[i][c4 * 4 + 1] = bf2f(uq.y) + bq[c4 * 4 + 1];
            q[i][c4 * 4 + 2] = bf2f(uq.z) + bq[c4 * 4 + 2];
            q[i][c4 * 4 + 3] = bf2f(uq.w) + bq[c4 * 4 + 3];
            k[i][c4 * 4 + 0] = bf2f(uk.x) + bk[c4 * 4 + 0];
            k[i][c4 * 4 + 1] = bf2f(uk.y) + bk[c4 * 4 + 1];
            k[i][c4 * 4 + 2] = bf2f(uk.z) + bk[c4 * 4 + 2];
            k[i][c4 * 4 + 3] = bf2f(uk.w) + bk[c4 * 4 + 3];
            v[i][c4 * 4 + 0] = bf2f(uv.x) + bv[c4 * 4 + 0];
            v[i][c4 * 4 + 1] = bf2f(uv.y) + bv[c4 * 4 + 1];
            v[i][c4 * 4 + 2] = bf2f(uv.z) + bv[c4 * 4 + 2];
            v[i][c4 * 4 + 3] = bf2f(uv.w) + bv[c4 * 4 + 3];
        }
    }
    const float isq = 0.1020620726159658f;   // 1/sqrt(96)
    float s[4][4];
    #pragma unroll
    for (int i = 0; i < 4; ++i)
        #pragma unroll
        for (int j = 0; j < 4; ++j) {
            float p = 0.f;
            #pragma unroll
            for (int c = 0; c < 12; ++c) p += q[i][c] * k[j][c];
            p += __shfl_xor(p, 1);
            p += __shfl_xor(p, 2);
            p += __shfl_xor(p, 4);
            s[i][j] = p * isq;
        }
    const float wt[4] = {0.4f, 0.3f, 0.2f, 0.1f};
    float wtil[4] = {0.f, 0.f, 0.f, 0.f};
    #pragma unroll
    for (int i = 0; i < 4; ++i) {
        float mx = fmaxf(fmaxf(s[i][0], s[i][1]), fmaxf(s[i][2], s[i][3]));
        float ex[4], den = 0.f;
        #pragma unroll
        for (int j = 0; j < 4; ++j) { ex[j] = __expf(s[i][j] - mx); den += ex[j]; }
        float idn = wt[i] / den;
        #pragma unroll
        for (int j = 0; j < 4; ++j) wtil[j] += ex[j] * idn;
    }
    unsigned short ob[12];
    #pragma unroll
    for (int c = 0; c < 12; ++c) {
        float o = wtil[0] * v[0][c] + wtil[1] * v[1][c] + wtil[2] * v[2][c] + wtil[3] * v[3][c];
        ob[c] = f2bf(o);
    }
    unsigned short* mbase = (unsigned short*)&g_mixed[(size_t)e * DD + d0];
    #pragma unroll
    for (int c4 = 0; c4 < 3; ++c4)
        *reinterpret_cast<ushort4*>(mbase + c4 * 4) =
            make_ushort4(ob[c4 * 4 + 0], ob[c4 * 4 + 1], ob[c4 * 4 + 2], ob[c4 * 4 + 3]);
}

// one wave per row: add out-proj bias, softplus scale, nan guard, L2-normalize
__global__ void k_norm(const float* __restrict__ number, const float* __restrict__ boundaries,
                       const float* __restrict__ out_proj_b,
                       const float* __restrict__ ms, const float* __restrict__ temp,
                       float* __restrict__ out) {
    const int wid = threadIdx.x >> 6, lane = threadIdx.x & 63;
    const int e = blockIdx.x * 4 + wid;
    const float x = number[e];
    int bin = 0;
    #pragma unroll
    for (int j = 0; j < 20; ++j) bin += (boundaries[j] < x) ? 1 : 0;
    bin = min(bin, 19);
    float z = ms[bin] / temp[0];
    float sc = (z > 20.f) ? z : log1pf(expf(z));
    const int d0 = lane * 12;
    const unsigned short* base = (const unsigned short*)&g_pre[(size_t)e * DD + d0];
    float o[12], ss = 0.f;
    #pragma unroll
    for (int c4 = 0; c4 < 3; ++c4) {
        ushort4 u = *reinterpret_cast<const ushort4*>(base + c4 * 4);
        float4 b = *reinterpret_cast<const float4*>(&out_proj_b[d0 + c4 * 4]);
        float p0 = (bf2f(u.x) + b.x) * sc;
        float p1 = (bf2f(u.y) + b.y) * sc;
        float p2 = (bf2f(u.z) + b.z) * sc;
        float p3 = (bf2f(u.w) + b.w) * sc;
        if (p0 != p0) p0 = 0.f;
        if (p1 != p1) p1 = 0.f;
        if (p2 != p2) p2 = 0.f;
        if (p3 != p3) p3 = 0.f;
        o[c4 * 4 + 0] = p0; o[c4 * 4 + 1] = p1; o[c4 * 4 + 2] = p2; o[c4 * 4 + 3] = p3;
        ss += p0 * p0 + p1 * p1 + p2 * p2 + p3 * p3;
    }
    #pragma unroll
    for (int ofs = 32; ofs; ofs >>= 1) ss += __shfl_xor(ss, ofs);
    float inv = 1.f / fmaxf(sqrtf(ss), 1e-12f);
    float* obase = &out[(size_t)e * DD + d0];
    #pragma unroll
    for (int c4 = 0; c4 < 3; ++c4)
        *reinterpret_cast<float4*>(obase + c4 * 4) =
            make_float4(o[c4 * 4 + 0] * inv, o[c4 * 4 + 1] * inv, o[c4 * 4 + 2] * inv, o[c4 * 4 + 3] * inv);
}

extern "C" void kernel_launch(void* const* d_in, const int* in_sizes, int n_in,
                              void* d_out, int out_size, void* d_ws, size_t ws_size,
                              hipStream_t stream) {
    const float* number      = (const float*)d_in[0];
    const float* boundaries  = (const float*)d_in[1];
    const float* mag_emb     = (const float*)d_in[2];
    const float* se_w1       = (const float*)d_in[3];
    const float* se_b1       = (const float*)d_in[4];
    const float* se_g1       = (const float*)d_in[5];
    const float* se_bt1      = (const float*)d_in[6];
    const float* se_w2       = (const float*)d_in[7];
    const float* se_b2       = (const float*)d_in[8];
    const float* ne_w        = (const float*)d_in[9];
    const float* ne_b        = (const float*)d_in[10];
    const float* ne_g        = (const float*)d_in[11];
    const float* ne_bt       = (const float*)d_in[12];
    const float* ce_w        = (const float*)d_in[13];
    const float* ce_b        = (const float*)d_in[14];
    const float* ce_g        = (const float*)d_in[15];
    const float* ce_bt       = (const float*)d_in[16];
    const float* in_proj_w   = (const float*)d_in[17];
    const float* in_proj_b   = (const float*)d_in[18];
    const float* out_proj_w  = (const float*)d_in[19];
    const float* out_proj_b  = (const float*)d_in[20];
    const float* mag_scale   = (const float*)d_in[21];
    const float* temperature = (const float*)d_in[22];
    float* out = (float*)d_out;

    k_absmax<<<1, 1024, 0, stream>>>(number);
    k_tables<<<2560, 256, 0, stream>>>(mag_emb, se_w1, se_b1, se_g1, se_bt1, se_w2, se_b2,
                                       ce_w, ce_b, ce_g, ce_bt, in_proj_w, out_proj_w);
    k_numenc<<<BB / 4, 256, 0, stream>>>(number, ne_w, ne_b, ne_g, ne_bt);
    gemm_bt<<<dim3(2304 / 128, MPAD / 128), 256, 0, stream>>>(0, 2304, DD);
    k_attn_mix<<<BB / 4, 256, 0, stream>>>(number, boundaries, in_proj_b);
    gemm_bt<<<dim3(DD / 128, BB / 128), 256, 0, stream>>>(1, DD, DD);
    k_norm<<<BB / 4, 256, 0, stream>>>(number, boundaries, out_proj_b, mag_scale, temperature, out);
}

// Round 12
// 170.396 us; speedup vs baseline: 1.3210x; 1.3210x over previous
//
#include <hip/hip_runtime.h>
#include <hip/hip_bf16.h>
#include <math.h>

#define BB 16384
#define DD 768
#define NG 2048                // grid points per sign
#define GR 4096                // grid rows (2 signs)
#define MROWS 4352             // 4096 grid + 84 tables + pad (17*256)

typedef __attribute__((ext_vector_type(8))) short bf16x8;
typedef __attribute__((ext_vector_type(4))) float f32x4;

// Static device scratch — referenced ONLY from device code.
__device__ short g_Abf[(size_t)MROWS * DD];         // bf16 feats: rows 0..4095 grid, 4096..4179 tables, pad 0
__device__ short g_W[(size_t)2304 * DD];            // bf16 in_proj_w
__device__ short g_WoutBf[(size_t)DD * DD];         // bf16 out_proj_w
__device__ short g_qkv[(size_t)MROWS * 2304];       // bf16 q|k|v per row (no bias)
__device__ short g_QKp[(size_t)16 * MROWS * 128];   // z<8: q+bq per head (K-pad 128); z>=8: k+bk
__device__ short g_TabP[(size_t)16 * 128 * 128];    // z<8: k_tab+bk; z>=8: q_tab+bq
__device__ float g_scoref[(size_t)16 * MROWS * 128];// z<8: u-scores; z>=8: w-scores (f32)
__device__ float g_sd[(size_t)MROWS * 8];           // per-head diagonal q_g.k_g
__device__ short g_mixed[(size_t)BB * DD];          // bf16 attention-mixed v (+bias)
__device__ short g_pre[(size_t)BB * DD];            // bf16 GEMM2 out (no bias)
__device__ float g_maxabs;

__device__ inline unsigned short f2bf(float x) {
    union { float f; unsigned u; } v; v.f = x;
    unsigned r = v.u + 0x7fffu + ((v.u >> 16) & 1u);
    return (unsigned short)(r >> 16);
}
__device__ inline float bf2f(unsigned short h) {
    union { unsigned u; float f; } v; v.u = ((unsigned)h) << 16;
    return v.f;
}

__device__ inline float gelu_exact(float x) {
    return 0.5f * x * (1.0f + erff(x * 0.70710678118654752440f));
}

__device__ inline float block_sum256(float v, float* sbuf) {
    #pragma unroll
    for (int o = 32; o; o >>= 1) v += __shfl_xor(v, o);
    __syncthreads();
    if ((threadIdx.x & 63) == 0) sbuf[threadIdx.x >> 6] = v;
    __syncthreads();
    return sbuf[0] + sbuf[1] + sbuf[2] + sbuf[3];
}

// single block, 1024 threads: max|x| -> g_maxabs
__global__ __launch_bounds__(1024) void k_absmax(const float* __restrict__ number) {
    const float4* n4 = reinterpret_cast<const float4*>(number);
    float v = 0.f;
    #pragma unroll
    for (int i = 0; i < 4; ++i) {
        float4 x = n4[threadIdx.x + 1024 * i];
        v = fmaxf(fmaxf(fabsf(x.x), fabsf(x.y)), fmaxf(fmaxf(fabsf(x.z), fabsf(x.w)), v));
    }
    #pragma unroll
    for (int o = 32; o; o >>= 1) v = fmaxf(v, __shfl_xor(v, o));
    __shared__ float sb[16];
    if ((threadIdx.x & 63) == 0) sb[threadIdx.x >> 6] = v;
    __syncthreads();
    if (threadIdx.x == 0) {
        float m = sb[0];
        #pragma unroll
        for (int i = 1; i < 16; ++i) m = fmaxf(m, sb[i]);
        g_maxabs = m;
    }
}

// blocks: 0-19 mag rows, 20-35 scale rows, 36-83 ctx rows (at GR+idx),
// 84-255 zero pad rows (4180..4351), 256+ weight cast.
__global__ void k_tables(const float* __restrict__ mag_emb,
                         const float* __restrict__ se_w1, const float* __restrict__ se_b1,
                         const float* __restrict__ se_g1, const float* __restrict__ se_bt1,
                         const float* __restrict__ se_w2, const float* __restrict__ se_b2,
                         const float* __restrict__ ce_w, const float* __restrict__ ce_b,
                         const float* __restrict__ ce_g, const float* __restrict__ ce_bt,
                         const float* __restrict__ in_proj_w, const float* __restrict__ out_proj_w) {
    __shared__ float sbuf[4];
    __shared__ float sh[192];
    const int t = threadIdx.x;
    const int blk = blockIdx.x;
    if (blk < 20) {
        #pragma unroll
        for (int i = 0; i < 3; ++i) {
            int d = t + 256 * i;
            g_Abf[(size_t)(GR + blk) * DD + d] = (short)f2bf(mag_emb[blk * DD + d]);
        }
    } else if (blk < 36) {
        int sfi = blk - 20;
        float sf = (float)(sfi - 10);
        float pre = 0.f;
        if (t < 192) pre = sf * se_w1[t] + se_b1[t];
        float s = block_sum256(t < 192 ? pre : 0.f, sbuf);
        float m = s / 192.f;
        float dd = (t < 192) ? (pre - m) : 0.f;
        float vv = block_sum256(dd * dd, sbuf);
        float inv = 1.f / sqrtf(vv / 192.f + 1e-5f);
        if (t < 192) sh[t] = gelu_exact((pre - m) * inv * se_g1[t] + se_bt1[t]);
        __syncthreads();
        #pragma unroll
        for (int i = 0; i < 3; ++i) {
            int d = t + 256 * i;
            float acc = se_b2[d];
            for (int j = 0; j < 192; ++j) acc += se_w2[d * 192 + j] * sh[j];
            g_Abf[(size_t)(GR + 20 + sfi) * DD + d] = (short)f2bf(acc);
        }
    } else if (blk < 84) {
        int c = blk - 36;
        int si = c >> 4, sfi = c & 15;
        float f0 = (float)(si - 1);
        float f1 = (float)(sfi - 10) / 16.f;
        float pre[3];
        float ps = 0.f;
        #pragma unroll
        for (int i = 0; i < 3; ++i) {
            int d = t + 256 * i;
            pre[i] = f0 * ce_w[2 * d] + f1 * ce_w[2 * d + 1] + ce_b[d];
            ps += pre[i];
        }
        float s = block_sum256(ps, sbuf);
        float m = s / 768.f;
        float qs = 0.f;
        #pragma unroll
        for (int i = 0; i < 3; ++i) { float dd = pre[i] - m; qs += dd * dd; }
        float vv = block_sum256(qs, sbuf);
        float inv = 1.f / sqrtf(vv / 768.f + 1e-5f);
        #pragma unroll
        for (int i = 0; i < 3; ++i) {
            int d = t + 256 * i;
            g_Abf[(size_t)(GR + 36 + c) * DD + d] =
                (short)f2bf(gelu_exact((pre[i] - m) * inv * ce_g[d] + ce_bt[d]));
        }
    } else if (blk < 256) {
        int row = GR + 84 + (blk - 84);    // 4180 .. 4351
        #pragma unroll
        for (int i = 0; i < 3; ++i) g_Abf[(size_t)row * DD + t + 256 * i] = 0;
    } else {
        int i = (blk - 256) * 256 + t;
        const bool second = (i >= 442368);
        const float* src = second ? out_proj_w : in_proj_w;
        short* dst = second ? g_WoutBf : g_W;
        int j = second ? (i - 442368) : i;
        const float4 v = *reinterpret_cast<const float4*>(&src[(size_t)j * 4]);
        ushort4 o;
        o.x = f2bf(v.x); o.y = f2bf(v.y); o.z = f2bf(v.z); o.w = f2bf(v.w);
        *reinterpret_cast<ushort4*>(&dst[(size_t)j * 4]) = o;
    }
}

// grid feat rows: one wave per row r in [0,4096). Row r: sign = (r>=NG)? -1:+1,
// t = (r%NG)*L/(NG-1) with L = log1p(max|x|); |x| = expm1(t). Same num_enc math
// as the reference, evaluated at synthetic (a,b). Linear interp over this grid
// has error ~(5e-3)^2 * O(1) ~ 3e-6 — far below bf16 noise.
__global__ void k_fgrid(const float* __restrict__ ne_w, const float* __restrict__ ne_b,
                        const float* __restrict__ ne_g, const float* __restrict__ ne_bt) {
    const int wid = threadIdx.x >> 6, lane = threadIdx.x & 63;
    const int r = blockIdx.x * 4 + wid;
    const float mx = g_maxabs;
    const float L = log1pf(mx);
    const float tt = (float)(r & (NG - 1)) * (L / (float)(NG - 1));
    const float ax = expm1f(tt);
    const float sgn = (r >= NG) ? -1.f : 1.f;
    const float a = sgn * ax / (mx + 1e-10f);
    const float b = tt / (L + 1e-10f);
    float pre[12];
    float s = 0.f;
    #pragma unroll
    for (int j = 0; j < 12; ++j) {
        int d = lane + 64 * j;
        float2 w = *reinterpret_cast<const float2*>(&ne_w[2 * d]);
        pre[j] = a * w.x + b * w.y + ne_b[d];
        s += pre[j];
    }
    #pragma unroll
    for (int o = 32; o; o >>= 1) s += __shfl_xor(s, o);
    float m = s / 768.f;
    float q = 0.f;
    #pragma unroll
    for (int j = 0; j < 12; ++j) { float dd = pre[j] - m; q += dd * dd; }
    #pragma unroll
    for (int o = 32; o; o >>= 1) q += __shfl_xor(q, o);
    float inv = 1.f / sqrtf(q / 768.f + 1e-5f);
    #pragma unroll
    for (int j = 0; j < 12; ++j) {
        int d = lane + 64 * j;
        g_Abf[(size_t)r * DD + d] = (short)f2bf(gelu_exact((pre[j] - m) * inv * ne_g[d] + ne_bt[d]));
    }
}

// C[m][n] = sum_k A[m][k]*B[n][k] (bf16 in, fp32 MFMA accum). R10 winner config:
// 256x128 tile, BK=64, 512 thr / 8 waves 4Mx2N, wave-tile 64x64.
// which==0: g_Abf(4352) @ g_W -> g_qkv bf16 (N=2304)
// which==1: g_mixed(16384) @ g_WoutBf -> g_pre bf16 (N=768)
// which==2: per-head score GEMMs, grid.z=16: g_QKp[z] @ g_TabP[z] -> g_scoref[z] F32
__global__ __launch_bounds__(512, 4) void gemm_bt(int which, int N, int K) {
    const int z = blockIdx.z;
    const short* A = (which == 0) ? g_Abf : (which == 1) ? g_mixed : g_QKp + (size_t)z * MROWS * 128;
    const short* B = (which == 0) ? g_W : (which == 1) ? g_WoutBf : g_TabP + (size_t)z * 128 * 128;
    short* C = (which == 0) ? g_qkv : g_pre;
    float* Cf = g_scoref + (size_t)z * MROWS * 128;

    __shared__ short As[256 * 64];
    __shared__ short Bs[128 * 64];
    const int t = threadIdx.x;

    const int GX = gridDim.x;
    const int nwg = GX * gridDim.y;
    const int lin = blockIdx.y * GX + blockIdx.x;
    const int qq = nwg >> 3, rr = nwg & 7;
    const int xcd = lin & 7, idx = lin >> 3;
    const int nl = (xcd < rr ? xcd * (qq + 1) : rr * (qq + 1) + (xcd - rr) * qq) + idx;
    const int m0 = (nl / GX) * 256, n0 = (nl % GX) * 128;

    const int wid = t >> 6, lane = t & 63;
    const int wm = wid >> 1, wn = wid & 1;
    const int fr = lane & 15, ks = lane >> 4;

    f32x4 acc[4][4];
    #pragma unroll
    for (int m = 0; m < 4; ++m)
        #pragma unroll
        for (int n = 0; n < 4; ++n) acc[m][n] = (f32x4){0.f, 0.f, 0.f, 0.f};

    for (int k0 = 0; k0 < K; k0 += 64) {
        #pragma unroll
        for (int i = 0; i < 4; ++i) {
            int L = t + 512 * i;
            int row = L >> 3, sp = L & 7;
            int s = sp ^ (row & 7);
            const short* srcA = A + (size_t)(m0 + row) * K + k0 + s * 8;
            __builtin_amdgcn_global_load_lds(
                (const __attribute__((address_space(1))) unsigned int*)srcA,
                (__attribute__((address_space(3))) unsigned int*)((char*)As + L * 16), 16, 0, 0);
        }
        #pragma unroll
        for (int i = 0; i < 2; ++i) {
            int L = t + 512 * i;
            int row = L >> 3, sp = L & 7;
            int s = sp ^ (row & 7);
            const short* srcB = B + (size_t)(n0 + row) * K + k0 + s * 8;
            __builtin_amdgcn_global_load_lds(
                (const __attribute__((address_space(1))) unsigned int*)srcB,
                (__attribute__((address_space(3))) unsigned int*)((char*)Bs + L * 16), 16, 0, 0);
        }
        __syncthreads();
        #pragma unroll
        for (int kk = 0; kk < 2; ++kk) {
            bf16x8 af[4], bfr[4];
            #pragma unroll
            for (int m = 0; m < 4; ++m) {
                int row = wm * 64 + m * 16 + fr;
                int off = row * 128 + ((((kk << 2) | ks) ^ (row & 7)) * 16);
                af[m] = *(const bf16x8*)((const char*)As + off);
            }
            #pragma unroll
            for (int n = 0; n < 4; ++n) {
                int row = wn * 64 + n * 16 + fr;
                int off = row * 128 + ((((kk << 2) | ks) ^ (row & 7)) * 16);
                bfr[n] = *(const bf16x8*)((const char*)Bs + off);
            }
            #pragma unroll
            for (int m = 0; m < 4; ++m)
                #pragma unroll
                for (int n = 0; n < 4; ++n)
                    acc[m][n] = __builtin_amdgcn_mfma_f32_16x16x32_bf16(af[m], bfr[n], acc[m][n], 0, 0, 0);
        }
        __syncthreads();
    }

    #pragma unroll
    for (int m = 0; m < 4; ++m)
        #pragma unroll
        for (int n = 0; n < 4; ++n)
            #pragma unroll
            for (int j = 0; j < 4; ++j) {
                int row = m0 + wm * 64 + m * 16 + ks * 4 + j;
                int col = n0 + wn * 64 + n * 16 + fr;
                if (which == 2) Cf[(size_t)row * N + col] = acc[m][n][j];
                else C[(size_t)row * N + col] = (short)f2bf(acc[m][n][j]);
            }
}

// repack q/k (+bias) per head with K padded 96->128 (zeros) for the score GEMMs.
// blocks 0..4351: g_QKp (16 z * 4352 rows * 16 chunks of 8); 4352..4479: g_TabP.
__global__ void k_repack(const float* __restrict__ in_proj_b) {
    const int idx = blockIdx.x * 256 + threadIdx.x;
    if (blockIdx.x < 4352) {
        const int z = idx / (MROWS * 16);
        const int rem = idx % (MROWS * 16);
        const int g = rem >> 4, c8 = rem & 15, d = c8 * 8;
        unsigned short o[8] = {0, 0, 0, 0, 0, 0, 0, 0};
        if (d < 96) {
            const int h = z & 7;
            const int off = (z < 8) ? 0 : 768;
            const float* bias = in_proj_b + off + h * 96 + d;
            const unsigned short* src = (const unsigned short*)g_qkv + (size_t)g * 2304 + off + h * 96 + d;
            #pragma unroll
            for (int c = 0; c < 8; ++c) o[c] = f2bf(bf2f(src[c]) + bias[c]);
        }
        *reinterpret_cast<bf16x8*>(g_QKp + (size_t)idx * 8) = *(const bf16x8*)o;
    } else {
        const int i2 = idx - 4352 * 256;           // < 32768
        const int z = i2 / (128 * 16);
        const int rem = i2 % (128 * 16);
        const int j = rem >> 4, c8 = rem & 15, d = c8 * 8;
        unsigned short o[8] = {0, 0, 0, 0, 0, 0, 0, 0};
        if (d < 96 && j < 84) {
            const int h = z & 7;
            const int off = (z < 8) ? 768 : 0;     // z<8: k_tab (u-GEMM B); z>=8: q_tab
            const float* bias = in_proj_b + off + h * 96 + d;
            const unsigned short* src = (const unsigned short*)g_qkv + (size_t)(GR + j) * 2304 + off + h * 96 + d;
            #pragma unroll
            for (int c = 0; c < 8; ++c) o[c] = f2bf(bf2f(src[c]) + bias[c]);
        }
        *reinterpret_cast<bf16x8*>(g_TabP + (size_t)i2 * 8) = *(const bf16x8*)o;
    }
}

// per-head diagonal: g_sd[g*8+h] = (q_g+bq).(k_g+bk) over head h. Wave per g.
__global__ void k_diag() {
    const int wid = threadIdx.x >> 6, lane = threadIdx.x & 63;
    const int g = blockIdx.x * 4 + wid;
    if (g >= GR + 84) return;
    const int h = lane >> 3, sub = lane & 7;
    const int d0 = sub * 16;
    const unsigned short* qp = (const unsigned short*)g_QKp + ((size_t)h * MROWS + g) * 128 + d0;
    const unsigned short* kp = (const unsigned short*)g_QKp + ((size_t)(8 + h) * MROWS + g) * 128 + d0;
    float s = 0.f;
    #pragma unroll
    for (int c = 0; c < 16; ++c) s += bf2f(qp[c]) * bf2f(kp[c]);
    s += __shfl_xor(s, 1);
    s += __shfl_xor(s, 2);
    s += __shfl_xor(s, 4);
    if (sub == 0) g_sd[(size_t)g * 8 + h] = s;
}

// per-element: exact bin/sfi/si, grid lerp of per-head scores + v row, softmax,
// mix -> g_mixed. One wave per element, lane owns 12 dims, head = lane>>3.
__global__ void k_attn2(const float* __restrict__ number, const float* __restrict__ boundaries,
                        const float* __restrict__ in_proj_b) {
    const int wid = threadIdx.x >> 6, lane = threadIdx.x & 63;
    const int e = blockIdx.x * 4 + wid;
    const float x = number[e];
    int bin = 0;
    #pragma unroll
    for (int j = 0; j < 20; ++j) bin += (boundaries[j] < x) ? 1 : 0;
    bin = min(bin, 19);
    float sf = floorf(log10f(fabsf(x) + 1e-10f));
    int sfi = min(max((int)sf + 10, 0), 15);
    int si = (x > 0.f) ? 2 : ((x < 0.f) ? 0 : 1);
    const int j3[3] = {bin, 20 + sfi, 36 + si * 16 + sfi};

    const float mx = g_maxabs;
    const float L = log1pf(mx);
    const float tt = log1pf(fabsf(x));
    float pos = tt * ((float)(NG - 1) / L);
    int i0 = (int)pos;
    i0 = min(max(i0, 0), NG - 2);
    const float w1 = pos - (float)i0, w0 = 1.f - w1;
    const int g0 = ((x < 0.f) ? NG : 0) + i0;

    const int h = lane >> 3;
    const float isq = 0.1020620726159658f;   // 1/sqrt(96)
    float s[4][4];
    s[0][0] = (w0 * g_sd[(size_t)g0 * 8 + h] + w1 * g_sd[(size_t)(g0 + 1) * 8 + h]) * isq;
    const size_t su0 = ((size_t)h * MROWS + g0) * 128;
    const size_t sw0 = ((size_t)(8 + h) * MROWS + g0) * 128;
    #pragma unroll
    for (int jj = 0; jj < 3; ++jj) {
        const int j = j3[jj];
        s[0][jj + 1] = (w0 * g_scoref[su0 + j] + w1 * g_scoref[su0 + 128 + j]) * isq;
        s[jj + 1][0] = (w0 * g_scoref[sw0 + j] + w1 * g_scoref[sw0 + 128 + j]) * isq;
    }
    #pragma unroll
    for (int ii = 0; ii < 3; ++ii)
        #pragma unroll
        for (int jj = 0; jj < 3; ++jj)
            s[ii + 1][jj + 1] = g_scoref[((size_t)h * MROWS + GR + j3[ii]) * 128 + j3[jj]] * isq;

    const float wt[4] = {0.4f, 0.3f, 0.2f, 0.1f};
    float wtil[4] = {0.f, 0.f, 0.f, 0.f};
    #pragma unroll
    for (int i = 0; i < 4; ++i) {
        float mxs = fmaxf(fmaxf(s[i][0], s[i][1]), fmaxf(s[i][2], s[i][3]));
        float ex[4], den = 0.f;
        #pragma unroll
        for (int j = 0; j < 4; ++j) { ex[j] = __expf(s[i][j] - mxs); den += ex[j]; }
        float idn = wt[i] / den;
        #pragma unroll
        for (int j = 0; j < 4; ++j) wtil[j] += ex[j] * idn;
    }

    const int d0 = lane * 12;
    float bv[12];
    #pragma unroll
    for (int c4 = 0; c4 < 3; ++c4) {
        float4 c = *reinterpret_cast<const float4*>(&in_proj_b[1536 + d0 + c4 * 4]);
        bv[c4 * 4 + 0] = c.x; bv[c4 * 4 + 1] = c.y; bv[c4 * 4 + 2] = c.z; bv[c4 * 4 + 3] = c.w;
    }
    float ve[12];
    {
        const unsigned short* r0 = (const unsigned short*)g_qkv + (size_t)g0 * 2304 + 1536 + d0;
        const unsigned short* r1 = r0 + 2304;
        #pragma unroll
        for (int c = 0; c < 12; ++c) ve[c] = w0 * bf2f(r0[c]) + w1 * bf2f(r1[c]) + bv[c];
    }
    float mixv[12];
    #pragma unroll
    for (int c = 0; c < 12; ++c) mixv[c] = wtil[0] * ve[c];
    #pragma unroll
    for (int jj = 0; jj < 3; ++jj) {
        const unsigned short* rt = (const unsigned short*)g_qkv + (size_t)(GR + j3[jj]) * 2304 + 1536 + d0;
        const float w = wtil[jj + 1];
        #pragma unroll
        for (int c = 0; c < 12; ++c) mixv[c] += w * (bf2f(rt[c]) + bv[c]);
    }
    unsigned short ob[12];
    #pragma unroll
    for (int c = 0; c < 12; ++c) ob[c] = f2bf(mixv[c]);
    unsigned short* mbase = (unsigned short*)g_mixed + (size_t)e * DD + d0;
    #pragma unroll
    for (int c4 = 0; c4 < 3; ++c4)
        *reinterpret_cast<ushort4*>(mbase + c4 * 4) =
            make_ushort4(ob[c4 * 4 + 0], ob[c4 * 4 + 1], ob[c4 * 4 + 2], ob[c4 * 4 + 3]);
}

// bias + NaN guard + L2 normalize. Softplus scale sc>0 provably cancels in
// normalize (out = v*sc/||v*sc|| = v/||v||) — dropped entirely.
__global__ void k_norm2(const float* __restrict__ out_proj_b, float* __restrict__ out) {
    const int wid = threadIdx.x >> 6, lane = threadIdx.x & 63;
    const int e = blockIdx.x * 4 + wid;
    const int d0 = lane * 12;
    const unsigned short* base = (const unsigned short*)g_pre + (size_t)e * DD + d0;
    float o[12], ss = 0.f;
    #pragma unroll
    for (int c4 = 0; c4 < 3; ++c4) {
        ushort4 u = *reinterpret_cast<const ushort4*>(base + c4 * 4);
        float4 b = *reinterpret_cast<const float4*>(&out_proj_b[d0 + c4 * 4]);
        float p0 = bf2f(u.x) + b.x;
        float p1 = bf2f(u.y) + b.y;
        float p2 = bf2f(u.z) + b.z;
        float p3 = bf2f(u.w) + b.w;
        if (p0 != p0) p0 = 0.f;
        if (p1 != p1) p1 = 0.f;
        if (p2 != p2) p2 = 0.f;
        if (p3 != p3) p3 = 0.f;
        o[c4 * 4 + 0] = p0; o[c4 * 4 + 1] = p1; o[c4 * 4 + 2] = p2; o[c4 * 4 + 3] = p3;
        ss += p0 * p0 + p1 * p1 + p2 * p2 + p3 * p3;
    }
    #pragma unroll
    for (int ofs = 32; ofs; ofs >>= 1) ss += __shfl_xor(ss, ofs);
    float inv = 1.f / fmaxf(sqrtf(ss), 1e-12f);
    float* obase = &out[(size_t)e * DD + d0];
    #pragma unroll
    for (int c4 = 0; c4 < 3; ++c4)
        *reinterpret_cast<float4*>(obase + c4 * 4) =
            make_float4(o[c4 * 4 + 0] * inv, o[c4 * 4 + 1] * inv, o[c4 * 4 + 2] * inv, o[c4 * 4 + 3] * inv);
}

extern "C" void kernel_launch(void* const* d_in, const int* in_sizes, int n_in,
                              void* d_out, int out_size, void* d_ws, size_t ws_size,
                              hipStream_t stream) {
    const float* number      = (const float*)d_in[0];
    const float* boundaries  = (const float*)d_in[1];
    const float* mag_emb     = (const float*)d_in[2];
    const float* se_w1       = (const float*)d_in[3];
    const float* se_b1       = (const float*)d_in[4];
    const float* se_g1       = (const float*)d_in[5];
    const float* se_bt1      = (const float*)d_in[6];
    const float* se_w2       = (const float*)d_in[7];
    const float* se_b2       = (const float*)d_in[8];
    const float* ne_w        = (const float*)d_in[9];
    const float* ne_b        = (const float*)d_in[10];
    const float* ne_g        = (const float*)d_in[11];
    const float* ne_bt       = (const float*)d_in[12];
    const float* ce_w        = (const float*)d_in[13];
    const float* ce_b        = (const float*)d_in[14];
    const float* ce_g        = (const float*)d_in[15];
    const float* ce_bt       = (const float*)d_in[16];
    const float* in_proj_w   = (const float*)d_in[17];
    const float* in_proj_b   = (const float*)d_in[18];
    const float* out_proj_w  = (const float*)d_in[19];
    const float* out_proj_b  = (const float*)d_in[20];
    float* out = (float*)d_out;

    k_absmax<<<1, 1024, 0, stream>>>(number);
    k_tables<<<2560, 256, 0, stream>>>(mag_emb, se_w1, se_b1, se_g1, se_bt1, se_w2, se_b2,
                                       ce_w, ce_b, ce_g, ce_bt, in_proj_w, out_proj_w);
    k_fgrid<<<GR / 4, 256, 0, stream>>>(ne_w, ne_b, ne_g, ne_bt);
    gemm_bt<<<dim3(2304 / 128, MROWS / 256, 1), 512, 0, stream>>>(0, 2304, DD);
    k_repack<<<4480, 256, 0, stream>>>(in_proj_b);
    gemm_bt<<<dim3(1, MROWS / 256, 16), 512, 0, stream>>>(2, 128, 128);
    k_diag<<<(GR + 84 + 3) / 4, 256, 0, stream>>>();
    k_attn2<<<BB / 4, 256, 0, stream>>>(number, boundaries, in_proj_b);
    gemm_bt<<<dim3(DD / 128, BB / 256, 1), 512, 0, stream>>>(1, DD, DD);
    k_norm2<<<BB / 4, 256, 0, stream>>>(out_proj_b, out);
}

// Round 13
// 137.988 us; speedup vs baseline: 1.6313x; 1.2349x over previous
//
#include <hip/hip_runtime.h>
#include <hip/hip_bf16.h>
#include <math.h>

#define BB 16384
#define DD 768
#define NG 512                 // grid points per sign
#define GR 1024                // grid rows (2 signs)
#define MROWS 1280             // 1024 grid + 84 tables + pad (5*256)

typedef __attribute__((ext_vector_type(8))) short bf16x8;
typedef __attribute__((ext_vector_type(4))) float f32x4;

// Static device scratch — referenced ONLY from device code.
__device__ short g_Abf[(size_t)MROWS * DD];         // bf16 feats: 0..1023 grid, 1024..1107 tables, pad 0
__device__ short g_W[(size_t)2304 * DD];            // bf16 in_proj_w
__device__ short g_WoutBf[(size_t)DD * DD];         // bf16 out_proj_w
__device__ short g_qkv[(size_t)MROWS * 2304];       // bf16 q|k|v per row (no bias)
__device__ short g_QKp[(size_t)16 * MROWS * 128];   // z<8: q+bq per head (K-pad 128); z>=8: k+bk
__device__ short g_TabP[(size_t)16 * 128 * 128];    // z<8: k_tab+bk; z>=8: q_tab+bq
__device__ float g_scoref[(size_t)16 * MROWS * 128];// z<8: u-scores; z>=8: w-scores (f32)
__device__ float g_sd[(size_t)MROWS * 8];           // per-head diagonal (q+bq).(k+bk)
__device__ short g_mixed[(size_t)BB * DD];          // bf16 attention-mixed v (+bias)
__device__ short g_pre[(size_t)BB * DD];            // bf16 GEMM2 out (no bias)
__device__ float g_maxabs;

__device__ inline unsigned short f2bf(float x) {
    union { float f; unsigned u; } v; v.f = x;
    unsigned r = v.u + 0x7fffu + ((v.u >> 16) & 1u);
    return (unsigned short)(r >> 16);
}
__device__ inline float bf2f(unsigned short h) {
    union { unsigned u; float f; } v; v.u = ((unsigned)h) << 16;
    return v.f;
}

__device__ inline float gelu_exact(float x) {
    return 0.5f * x * (1.0f + erff(x * 0.70710678118654752440f));
}

__device__ inline float block_sum256(float v, float* sbuf) {
    #pragma unroll
    for (int o = 32; o; o >>= 1) v += __shfl_xor(v, o);
    __syncthreads();
    if ((threadIdx.x & 63) == 0) sbuf[threadIdx.x >> 6] = v;
    __syncthreads();
    return sbuf[0] + sbuf[1] + sbuf[2] + sbuf[3];
}

// single block, 1024 threads: max|x| -> g_maxabs
__global__ __launch_bounds__(1024) void k_absmax(const float* __restrict__ number) {
    const float4* n4 = reinterpret_cast<const float4*>(number);
    float v = 0.f;
    #pragma unroll
    for (int i = 0; i < 4; ++i) {
        float4 x = n4[threadIdx.x + 1024 * i];
        v = fmaxf(fmaxf(fabsf(x.x), fabsf(x.y)), fmaxf(fmaxf(fabsf(x.z), fabsf(x.w)), v));
    }
    #pragma unroll
    for (int o = 32; o; o >>= 1) v = fmaxf(v, __shfl_xor(v, o));
    __shared__ float sb[16];
    if ((threadIdx.x & 63) == 0) sb[threadIdx.x >> 6] = v;
    __syncthreads();
    if (threadIdx.x == 0) {
        float m = sb[0];
        #pragma unroll
        for (int i = 1; i < 16; ++i) m = fmaxf(m, sb[i]);
        g_maxabs = m;
    }
}

// blocks: 0-19 mag rows, 20-35 scale rows, 36-83 ctx rows (at GR+idx),
// 84-255 zero pad rows (1108..1279), 256-2559 weight cast, 2560-2815 fgrid rows.
__global__ void k_tables(const float* __restrict__ mag_emb,
                         const float* __restrict__ se_w1, const float* __restrict__ se_b1,
                         const float* __restrict__ se_g1, const float* __restrict__ se_bt1,
                         const float* __restrict__ se_w2, const float* __restrict__ se_b2,
                         const float* __restrict__ ce_w, const float* __restrict__ ce_b,
                         const float* __restrict__ ce_g, const float* __restrict__ ce_bt,
                         const float* __restrict__ in_proj_w, const float* __restrict__ out_proj_w,
                         const float* __restrict__ ne_w, const float* __restrict__ ne_b,
                         const float* __restrict__ ne_g, const float* __restrict__ ne_bt) {
    __shared__ float sbuf[4];
    __shared__ float sh[192];
    const int t = threadIdx.x;
    const int blk = blockIdx.x;
    if (blk < 20) {
        #pragma unroll
        for (int i = 0; i < 3; ++i) {
            int d = t + 256 * i;
            g_Abf[(size_t)(GR + blk) * DD + d] = (short)f2bf(mag_emb[blk * DD + d]);
        }
    } else if (blk < 36) {
        int sfi = blk - 20;
        float sf = (float)(sfi - 10);
        float pre = 0.f;
        if (t < 192) pre = sf * se_w1[t] + se_b1[t];
        float s = block_sum256(t < 192 ? pre : 0.f, sbuf);
        float m = s / 192.f;
        float dd = (t < 192) ? (pre - m) : 0.f;
        float vv = block_sum256(dd * dd, sbuf);
        float inv = 1.f / sqrtf(vv / 192.f + 1e-5f);
        if (t < 192) sh[t] = gelu_exact((pre - m) * inv * se_g1[t] + se_bt1[t]);
        __syncthreads();
        #pragma unroll
        for (int i = 0; i < 3; ++i) {
            int d = t + 256 * i;
            float acc = se_b2[d];
            for (int j = 0; j < 192; ++j) acc += se_w2[d * 192 + j] * sh[j];
            g_Abf[(size_t)(GR + 20 + sfi) * DD + d] = (short)f2bf(acc);
        }
    } else if (blk < 84) {
        int c = blk - 36;
        int si = c >> 4, sfi = c & 15;
        float f0 = (float)(si - 1);
        float f1 = (float)(sfi - 10) / 16.f;
        float pre[3];
        float ps = 0.f;
        #pragma unroll
        for (int i = 0; i < 3; ++i) {
            int d = t + 256 * i;
            pre[i] = f0 * ce_w[2 * d] + f1 * ce_w[2 * d + 1] + ce_b[d];
            ps += pre[i];
        }
        float s = block_sum256(ps, sbuf);
        float m = s / 768.f;
        float qs = 0.f;
        #pragma unroll
        for (int i = 0; i < 3; ++i) { float dd = pre[i] - m; qs += dd * dd; }
        float vv = block_sum256(qs, sbuf);
        float inv = 1.f / sqrtf(vv / 768.f + 1e-5f);
        #pragma unroll
        for (int i = 0; i < 3; ++i) {
            int d = t + 256 * i;
            g_Abf[(size_t)(GR + 36 + c) * DD + d] =
                (short)f2bf(gelu_exact((pre[i] - m) * inv * ce_g[d] + ce_bt[d]));
        }
    } else if (blk < 256) {
        int row = GR + 84 + (blk - 84);    // 1108 .. 1279
        #pragma unroll
        for (int i = 0; i < 3; ++i) g_Abf[(size_t)row * DD + t + 256 * i] = 0;
    } else if (blk < 2560) {
        int i = (blk - 256) * 256 + t;
        const bool second = (i >= 442368);
        const float* src = second ? out_proj_w : in_proj_w;
        short* dst = second ? g_WoutBf : g_W;
        int j = second ? (i - 442368) : i;
        const float4 v = *reinterpret_cast<const float4*>(&src[(size_t)j * 4]);
        ushort4 o;
        o.x = f2bf(v.x); o.y = f2bf(v.y); o.z = f2bf(v.z); o.w = f2bf(v.w);
        *reinterpret_cast<ushort4*>(&dst[(size_t)j * 4]) = o;
    } else {
        // fgrid: one wave per row r in [0,1024). sign = (r>=NG)? -1:+1,
        // t = (r%NG)*L/(NG-1), |x| = expm1(t). Interp err ~(L/NG)^2/8 ~1e-4.
        const int wid = t >> 6, lane = t & 63;
        const int r = (blk - 2560) * 4 + wid;
        const float mx = g_maxabs;
        const float L = log1pf(mx);
        const float tt = (float)(r & (NG - 1)) * (L / (float)(NG - 1));
        const float ax = expm1f(tt);
        const float sgn = (r >= NG) ? -1.f : 1.f;
        const float a = sgn * ax / (mx + 1e-10f);
        const float b = tt / (L + 1e-10f);
        float pre[12];
        float s = 0.f;
        #pragma unroll
        for (int j = 0; j < 12; ++j) {
            int d = lane + 64 * j;
            float2 w = *reinterpret_cast<const float2*>(&ne_w[2 * d]);
            pre[j] = a * w.x + b * w.y + ne_b[d];
            s += pre[j];
        }
        #pragma unroll
        for (int o = 32; o; o >>= 1) s += __shfl_xor(s, o);
        float m = s / 768.f;
        float q = 0.f;
        #pragma unroll
        for (int j = 0; j < 12; ++j) { float dd = pre[j] - m; q += dd * dd; }
        #pragma unroll
        for (int o = 32; o; o >>= 1) q += __shfl_xor(q, o);
        float inv = 1.f / sqrtf(q / 768.f + 1e-5f);
        #pragma unroll
        for (int j = 0; j < 12; ++j) {
            int d = lane + 64 * j;
            g_Abf[(size_t)r * DD + d] = (short)f2bf(gelu_exact((pre[j] - m) * inv * ne_g[d] + ne_bt[d]));
        }
    }
}

// C[m][n] = sum_k A[m][k]*B[n][k] (bf16 in, fp32 MFMA accum). R10 winner config:
// 256x128 tile, BK=64, 512 thr / 8 waves 4Mx2N, wave-tile 64x64.
// which==0: g_Abf(1280) @ g_W -> g_qkv bf16 (N=2304)
// which==1: g_mixed(16384) @ g_WoutBf -> g_pre bf16 (N=768)
// which==2: per-head score GEMMs, grid.z=16: g_QKp[z] @ g_TabP[z] -> g_scoref[z] F32
__global__ __launch_bounds__(512, 4) void gemm_bt(int which, int N, int K) {
    const int z = blockIdx.z;
    const short* A = (which == 0) ? g_Abf : (which == 1) ? g_mixed : g_QKp + (size_t)z * MROWS * 128;
    const short* B = (which == 0) ? g_W : (which == 1) ? g_WoutBf : g_TabP + (size_t)z * 128 * 128;
    short* C = (which == 0) ? g_qkv : g_pre;
    float* Cf = g_scoref + (size_t)z * MROWS * 128;

    __shared__ short As[256 * 64];
    __shared__ short Bs[128 * 64];
    const int t = threadIdx.x;

    const int GX = gridDim.x;
    const int nwg = GX * gridDim.y;
    const int lin = blockIdx.y * GX + blockIdx.x;
    const int qq = nwg >> 3, rr = nwg & 7;
    const int xcd = lin & 7, idx = lin >> 3;
    const int nl = (xcd < rr ? xcd * (qq + 1) : rr * (qq + 1) + (xcd - rr) * qq) + idx;
    const int m0 = (nl / GX) * 256, n0 = (nl % GX) * 128;

    const int wid = t >> 6, lane = t & 63;
    const int wm = wid >> 1, wn = wid & 1;
    const int fr = lane & 15, ks = lane >> 4;

    f32x4 acc[4][4];
    #pragma unroll
    for (int m = 0; m < 4; ++m)
        #pragma unroll
        for (int n = 0; n < 4; ++n) acc[m][n] = (f32x4){0.f, 0.f, 0.f, 0.f};

    for (int k0 = 0; k0 < K; k0 += 64) {
        #pragma unroll
        for (int i = 0; i < 4; ++i) {
            int L = t + 512 * i;
            int row = L >> 3, sp = L & 7;
            int s = sp ^ (row & 7);
            const short* srcA = A + (size_t)(m0 + row) * K + k0 + s * 8;
            __builtin_amdgcn_global_load_lds(
                (const __attribute__((address_space(1))) unsigned int*)srcA,
                (__attribute__((address_space(3))) unsigned int*)((char*)As + L * 16), 16, 0, 0);
        }
        #pragma unroll
        for (int i = 0; i < 2; ++i) {
            int L = t + 512 * i;
            int row = L >> 3, sp = L & 7;
            int s = sp ^ (row & 7);
            const short* srcB = B + (size_t)(n0 + row) * K + k0 + s * 8;
            __builtin_amdgcn_global_load_lds(
                (const __attribute__((address_space(1))) unsigned int*)srcB,
                (__attribute__((address_space(3))) unsigned int*)((char*)Bs + L * 16), 16, 0, 0);
        }
        __syncthreads();
        #pragma unroll
        for (int kk = 0; kk < 2; ++kk) {
            bf16x8 af[4], bfr[4];
            #pragma unroll
            for (int m = 0; m < 4; ++m) {
                int row = wm * 64 + m * 16 + fr;
                int off = row * 128 + ((((kk << 2) | ks) ^ (row & 7)) * 16);
                af[m] = *(const bf16x8*)((const char*)As + off);
            }
            #pragma unroll
            for (int n = 0; n < 4; ++n) {
                int row = wn * 64 + n * 16 + fr;
                int off = row * 128 + ((((kk << 2) | ks) ^ (row & 7)) * 16);
                bfr[n] = *(const bf16x8*)((const char*)Bs + off);
            }
            #pragma unroll
            for (int m = 0; m < 4; ++m)
                #pragma unroll
                for (int n = 0; n < 4; ++n)
                    acc[m][n] = __builtin_amdgcn_mfma_f32_16x16x32_bf16(af[m], bfr[n], acc[m][n], 0, 0, 0);
        }
        __syncthreads();
    }

    #pragma unroll
    for (int m = 0; m < 4; ++m)
        #pragma unroll
        for (int n = 0; n < 4; ++n)
            #pragma unroll
            for (int j = 0; j < 4; ++j) {
                int row = m0 + wm * 64 + m * 16 + ks * 4 + j;
                int col = n0 + wn * 64 + n * 16 + fr;
                if (which == 2) Cf[(size_t)row * N + col] = acc[m][n][j];
                else C[(size_t)row * N + col] = (short)f2bf(acc[m][n][j]);
            }
}

// repack q/k (+bias) per head (K pad 96->128) + per-head diagonal.
// blocks 0..1279: g_QKp; 1280..1407: g_TabP; 1408..1684: diag (from g_qkv, fp32 bias).
__global__ void k_repack(const float* __restrict__ in_proj_b) {
    const int blk = blockIdx.x;
    if (blk < 1280) {
        const int idx = blk * 256 + threadIdx.x;
        const int z = idx / (MROWS * 16);
        const int rem = idx % (MROWS * 16);
        const int g = rem >> 4, c8 = rem & 15, d = c8 * 8;
        unsigned short o[8] = {0, 0, 0, 0, 0, 0, 0, 0};
        if (d < 96) {
            const int h = z & 7;
            const int off = (z < 8) ? 0 : 768;
            const float* bias = in_proj_b + off + h * 96 + d;
            const unsigned short* src = (const unsigned short*)g_qkv + (size_t)g * 2304 + off + h * 96 + d;
            #pragma unroll
            for (int c = 0; c < 8; ++c) o[c] = f2bf(bf2f(src[c]) + bias[c]);
        }
        *reinterpret_cast<bf16x8*>(g_QKp + (size_t)idx * 8) = *(const bf16x8*)o;
    } else if (blk < 1408) {
        const int i2 = (blk - 1280) * 256 + threadIdx.x;   // < 32768
        const int z = i2 / (128 * 16);
        const int rem = i2 % (128 * 16);
        const int j = rem >> 4, c8 = rem & 15, d = c8 * 8;
        unsigned short o[8] = {0, 0, 0, 0, 0, 0, 0, 0};
        if (d < 96 && j < 84) {
            const int h = z & 7;
            const int off = (z < 8) ? 768 : 0;     // z<8: k_tab (u-GEMM B); z>=8: q_tab
            const float* bias = in_proj_b + off + h * 96 + d;
            const unsigned short* src = (const unsigned short*)g_qkv + (size_t)(GR + j) * 2304 + off + h * 96 + d;
            #pragma unroll
            for (int c = 0; c < 8; ++c) o[c] = f2bf(bf2f(src[c]) + bias[c]);
        }
        *reinterpret_cast<bf16x8*>(g_TabP + (size_t)i2 * 8) = *(const bf16x8*)o;
    } else {
        // diag: g_sd[g*8+h] = (q_g+bq).(k_g+bk) over head h. Wave per row g.
        const int wid = threadIdx.x >> 6, lane = threadIdx.x & 63;
        const int g = (blk - 1408) * 4 + wid;
        if (g >= GR + 84) return;
        const int h = lane >> 3, sub = lane & 7;
        const int d0 = h * 96 + sub * 12;
        const unsigned short* qrow = (const unsigned short*)g_qkv + (size_t)g * 2304 + d0;
        const unsigned short* krow = qrow + 768;
        const float* bq = in_proj_b + d0;
        const float* bk = in_proj_b + 768 + d0;
        float s = 0.f;
        #pragma unroll
        for (int c = 0; c < 12; ++c)
            s += (bf2f(qrow[c]) + bq[c]) * (bf2f(krow[c]) + bk[c]);
        s += __shfl_xor(s, 1);
        s += __shfl_xor(s, 2);
        s += __shfl_xor(s, 4);
        if (sub == 0) g_sd[(size_t)g * 8 + h] = s;
    }
}

// per-element: exact bin/sfi/si, grid lerp of per-head scores + v row, softmax,
// mix -> g_mixed. One wave per element, lane owns 12 dims, head = lane>>3.
__global__ void k_attn2(const float* __restrict__ number, const float* __restrict__ boundaries,
                        const float* __restrict__ in_proj_b) {
    const int wid = threadIdx.x >> 6, lane = threadIdx.x & 63;
    const int e = blockIdx.x * 4 + wid;
    const float x = number[e];
    int bin = 0;
    #pragma unroll
    for (int j = 0; j < 20; ++j) bin += (boundaries[j] < x) ? 1 : 0;
    bin = min(bin, 19);
    float sf = floorf(log10f(fabsf(x) + 1e-10f));
    int sfi = min(max((int)sf + 10, 0), 15);
    int si = (x > 0.f) ? 2 : ((x < 0.f) ? 0 : 1);
    const int j3[3] = {bin, 20 + sfi, 36 + si * 16 + sfi};

    const float mx = g_maxabs;
    const float L = log1pf(mx);
    const float tt = log1pf(fabsf(x));
    float pos = tt * ((float)(NG - 1) / L);
    int i0 = (int)pos;
    i0 = min(max(i0, 0), NG - 2);
    const float w1 = pos - (float)i0, w0 = 1.f - w1;
    const int g0 = ((x < 0.f) ? NG : 0) + i0;

    const int h = lane >> 3;
    const float isq = 0.1020620726159658f;   // 1/sqrt(96)
    float s[4][4];
    s[0][0] = (w0 * g_sd[(size_t)g0 * 8 + h] + w1 * g_sd[(size_t)(g0 + 1) * 8 + h]) * isq;
    const size_t su0 = ((size_t)h * MROWS + g0) * 128;
    const size_t sw0 = ((size_t)(8 + h) * MROWS + g0) * 128;
    #pragma unroll
    for (int jj = 0; jj < 3; ++jj) {
        const int j = j3[jj];
        s[0][jj + 1] = (w0 * g_scoref[su0 + j] + w1 * g_scoref[su0 + 128 + j]) * isq;
        s[jj + 1][0] = (w0 * g_scoref[sw0 + j] + w1 * g_scoref[sw0 + 128 + j]) * isq;
    }
    #pragma unroll
    for (int ii = 0; ii < 3; ++ii)
        #pragma unroll
        for (int jj = 0; jj < 3; ++jj)
            s[ii + 1][jj + 1] = g_scoref[((size_t)h * MROWS + GR + j3[ii]) * 128 + j3[jj]] * isq;

    const float wt[4] = {0.4f, 0.3f, 0.2f, 0.1f};
    float wtil[4] = {0.f, 0.f, 0.f, 0.f};
    #pragma unroll
    for (int i = 0; i < 4; ++i) {
        float mxs = fmaxf(fmaxf(s[i][0], s[i][1]), fmaxf(s[i][2], s[i][3]));
        float ex[4], den = 0.f;
        #pragma unroll
        for (int j = 0; j < 4; ++j) { ex[j] = __expf(s[i][j] - mxs); den += ex[j]; }
        float idn = wt[i] / den;
        #pragma unroll
        for (int j = 0; j < 4; ++j) wtil[j] += ex[j] * idn;
    }

    const int d0 = lane * 12;
    float bv[12];
    #pragma unroll
    for (int c4 = 0; c4 < 3; ++c4) {
        float4 c = *reinterpret_cast<const float4*>(&in_proj_b[1536 + d0 + c4 * 4]);
        bv[c4 * 4 + 0] = c.x; bv[c4 * 4 + 1] = c.y; bv[c4 * 4 + 2] = c.z; bv[c4 * 4 + 3] = c.w;
    }
    float ve[12];
    {
        const unsigned short* r0 = (const unsigned short*)g_qkv + (size_t)g0 * 2304 + 1536 + d0;
        const unsigned short* r1 = r0 + 2304;
        #pragma unroll
        for (int c = 0; c < 12; ++c) ve[c] = w0 * bf2f(r0[c]) + w1 * bf2f(r1[c]) + bv[c];
    }
    float mixv[12];
    #pragma unroll
    for (int c = 0; c < 12; ++c) mixv[c] = wtil[0] * ve[c];
    #pragma unroll
    for (int jj = 0; jj < 3; ++jj) {
        const unsigned short* rt = (const unsigned short*)g_qkv + (size_t)(GR + j3[jj]) * 2304 + 1536 + d0;
        const float w = wtil[jj + 1];
        #pragma unroll
        for (int c = 0; c < 12; ++c) mixv[c] += w * (bf2f(rt[c]) + bv[c]);
    }
    unsigned short ob[12];
    #pragma unroll
    for (int c = 0; c < 12; ++c) ob[c] = f2bf(mixv[c]);
    unsigned short* mbase = (unsigned short*)g_mixed + (size_t)e * DD + d0;
    #pragma unroll
    for (int c4 = 0; c4 < 3; ++c4)
        *reinterpret_cast<ushort4*>(mbase + c4 * 4) =
            make_ushort4(ob[c4 * 4 + 0], ob[c4 * 4 + 1], ob[c4 * 4 + 2], ob[c4 * 4 + 3]);
}

// bias + NaN guard + L2 normalize (softplus scale cancels in normalize).
__global__ void k_norm2(const float* __restrict__ out_proj_b, float* __restrict__ out) {
    const int wid = threadIdx.x >> 6, lane = threadIdx.x & 63;
    const int e = blockIdx.x * 4 + wid;
    const int d0 = lane * 12;
    const unsigned short* base = (const unsigned short*)g_pre + (size_t)e * DD + d0;
    float o[12], ss = 0.f;
    #pragma unroll
    for (int c4 = 0; c4 < 3; ++c4) {
        ushort4 u = *reinterpret_cast<const ushort4*>(base + c4 * 4);
        float4 b = *reinterpret_cast<const float4*>(&out_proj_b[d0 + c4 * 4]);
        float p0 = bf2f(u.x) + b.x;
        float p1 = bf2f(u.y) + b.y;
        float p2 = bf2f(u.z) + b.z;
        float p3 = bf2f(u.w) + b.w;
        if (p0 != p0) p0 = 0.f;
        if (p1 != p1) p1 = 0.f;
        if (p2 != p2) p2 = 0.f;
        if (p3 != p3) p3 = 0.f;
        o[c4 * 4 + 0] = p0; o[c4 * 4 + 1] = p1; o[c4 * 4 + 2] = p2; o[c4 * 4 + 3] = p3;
        ss += p0 * p0 + p1 * p1 + p2 * p2 + p3 * p3;
    }
    #pragma unroll
    for (int ofs = 32; ofs; ofs >>= 1) ss += __shfl_xor(ss, ofs);
    float inv = 1.f / fmaxf(sqrtf(ss), 1e-12f);
    float* obase = &out[(size_t)e * DD + d0];
    #pragma unroll
    for (int c4 = 0; c4 < 3; ++c4)
        *reinterpret_cast<float4*>(obase + c4 * 4) =
            make_float4(o[c4 * 4 + 0] * inv, o[c4 * 4 + 1] * inv, o[c4 * 4 + 2] * inv, o[c4 * 4 + 3] * inv);
}

extern "C" void kernel_launch(void* const* d_in, const int* in_sizes, int n_in,
                              void* d_out, int out_size, void* d_ws, size_t ws_size,
                              hipStream_t stream) {
    const float* number      = (const float*)d_in[0];
    const float* boundaries  = (const float*)d_in[1];
    const float* mag_emb     = (const float*)d_in[2];
    const float* se_w1       = (const float*)d_in[3];
    const float* se_b1       = (const float*)d_in[4];
    const float* se_g1       = (const float*)d_in[5];
    const float* se_bt1      = (const float*)d_in[6];
    const float* se_w2       = (const float*)d_in[7];
    const float* se_b2       = (const float*)d_in[8];
    const float* ne_w        = (const float*)d_in[9];
    const float* ne_b        = (const float*)d_in[10];
    const float* ne_g        = (const float*)d_in[11];
    const float* ne_bt       = (const float*)d_in[12];
    const float* ce_w        = (const float*)d_in[13];
    const float* ce_b        = (const float*)d_in[14];
    const float* ce_g        = (const float*)d_in[15];
    const float* ce_bt       = (const float*)d_in[16];
    const float* in_proj_w   = (const float*)d_in[17];
    const float* in_proj_b   = (const float*)d_in[18];
    const float* out_proj_w  = (const float*)d_in[19];
    const float* out_proj_b  = (const float*)d_in[20];
    float* out = (float*)d_out;

    k_absmax<<<1, 1024, 0, stream>>>(number);
    k_tables<<<2816, 256, 0, stream>>>(mag_emb, se_w1, se_b1, se_g1, se_bt1, se_w2, se_b2,
                                       ce_w, ce_b, ce_g, ce_bt, in_proj_w, out_proj_w,
                                       ne_w, ne_b, ne_g, ne_bt);
    gemm_bt<<<dim3(2304 / 128, MROWS / 256, 1), 512, 0, stream>>>(0, 2304, DD);
    k_repack<<<1685, 256, 0, stream>>>(in_proj_b);
    gemm_bt<<<dim3(1, MROWS / 256, 16), 512, 0, stream>>>(2, 128, 128);
    k_attn2<<<BB / 4, 256, 0, stream>>>(number, boundaries, in_proj_b);
    gemm_bt<<<dim3(DD / 128, BB / 256, 1), 512, 0, stream>>>(1, DD, DD);
    k_norm2<<<BB / 4, 256, 0, stream>>>(out_proj_b, out);
}